// Round 1
// baseline (622.345 us; speedup 1.0000x reference)
//
#include <hip/hip_runtime.h>

// CrossAttention decode, algebraically collapsed:
//   q[b,h,:]   = ((x1@We1+be1)@Wq+bq) head-sliced                      [16,16,64]
//   u[b,h,c]   = sum_d Wk[c,h*64+d]*q[b,h,d]                           [256,1024]
//   w[b,h,i]   = sum_c We2[i,c]*u[b,h,c]        (K-proj folded)        [256,512]
//   cK[b,h]    = be2.u + q.bk_h
//   score[b,h,s] = x2[b,s,:].w[b,h,:] + cK      (134MB stream #1)
//   a = softmax(score/8)
//   g[b,h,i]   = sum_s a[b,h,s]*x3[b,s,i]       (134MB stream #2)
//   G2[b,h,c]  = sum_i g[i]*We2[i,c] + be2[c]
//   av[b,h,d]  = sum_c G2[c]*Wv[c,h*64+d] + bv
//   out        = av_flat@Wo + bo
// All fp32. Roofline = 2x134MB HBM reads ~= 43us.

#define DIN 512
#define DD  1024
#define NH  16
#define HD  64
#define BB  16
#define SS  4096

__device__ __forceinline__ int wave_id() {
    return __builtin_amdgcn_readfirstlane((int)(threadIdx.x >> 6));
}

// out[b][c] = sum_k in[b][k] * W[k][c] + bias[c];  W is [K][1024] row-major.
// grid (1024/256, 16), block 256. in-row loads are wave-uniform -> s_load.
template <int K>
__global__ __launch_bounds__(256) void k_rowvec_mm(const float* __restrict__ in,
                                                   const float* __restrict__ W,
                                                   const float* __restrict__ bias,
                                                   float* __restrict__ out) {
    const int b = blockIdx.y;
    const int c = blockIdx.x * 256 + threadIdx.x;
    const float* xr = in + (size_t)b * K;
    float a0 = bias[c], a1 = 0.f, a2 = 0.f, a3 = 0.f;
#pragma unroll 4
    for (int i = 0; i < K; i += 4) {
        a0 += xr[i + 0] * W[(size_t)(i + 0) * DD + c];
        a1 += xr[i + 1] * W[(size_t)(i + 1) * DD + c];
        a2 += xr[i + 2] * W[(size_t)(i + 2) * DD + c];
        a3 += xr[i + 3] * W[(size_t)(i + 3) * DD + c];
    }
    out[(size_t)b * DD + c] = (a0 + a1) + (a2 + a3);
}

// u[pair][c] = sum_d Wk[c][h*64+d]*q[b][h*64+d];  cK[pair] = be2.u + q.bk_h
// grid (16 h, 16 b), block 256.
__global__ __launch_bounds__(256) void k_u(const float* __restrict__ q,
                                           const float* __restrict__ Wk,
                                           const float* __restrict__ bk,
                                           const float* __restrict__ be2,
                                           float* __restrict__ u,
                                           float* __restrict__ cK) {
    const int h = blockIdx.x, b = blockIdx.y;
    const int pair = b * NH + h;
    const float* qv = q + (size_t)b * DD + h * HD;  // uniform
    float ckp = 0.f;
#pragma unroll
    for (int kk = 0; kk < 4; ++kk) {
        const int c = kk * 256 + threadIdx.x;
        const float* wr = Wk + (size_t)c * DD + h * HD;
        float acc = 0.f;
#pragma unroll
        for (int d = 0; d < HD; d += 4) {
            float4 w4 = *(const float4*)(wr + d);
            acc += qv[d] * w4.x + qv[d + 1] * w4.y + qv[d + 2] * w4.z + qv[d + 3] * w4.w;
        }
        u[(size_t)pair * DD + c] = acc;
        ckp += be2[c] * acc;
    }
    if (threadIdx.x < HD) ckp += qv[threadIdx.x] * bk[h * HD + threadIdx.x];
    __shared__ float red[256];
    red[threadIdx.x] = ckp;
    __syncthreads();
    for (int s = 128; s > 0; s >>= 1) {
        if (threadIdx.x < (unsigned)s) red[threadIdx.x] += red[threadIdx.x + s];
        __syncthreads();
    }
    if (threadIdx.x == 0) cK[pair] = red[0];
}

// w[p][i] = sum_c u[p][c]*We2[i][c].  grid (512/64, 256/8), block 256.
// Each wave: 2 pairs (uniform u -> s_load), lane streams We2 row i.
__global__ __launch_bounds__(256) void k_w(const float* __restrict__ u,
                                           const float* __restrict__ We2,
                                           float* __restrict__ w) {
    const int i = blockIdx.x * 64 + (threadIdx.x & 63);
    const int p0 = blockIdx.y * 8 + wave_id() * 2;
    const float* br = We2 + (size_t)i * DD;
    const float* a0 = u + (size_t)p0 * DD;  // uniform
    const float* a1 = a0 + DD;
    float acc0 = 0.f, acc1 = 0.f;
#pragma unroll 4
    for (int c = 0; c < DD; c += 4) {
        float4 b4 = *(const float4*)(br + c);
        float4 ua = *(const float4*)(a0 + c);
        float4 ub = *(const float4*)(a1 + c);
        acc0 += ua.x * b4.x + ua.y * b4.y + ua.z * b4.z + ua.w * b4.w;
        acc1 += ub.x * b4.x + ub.y * b4.y + ub.z * b4.z + ub.w * b4.w;
    }
    w[(size_t)p0 * DIN + i] = acc0;
    w[(size_t)(p0 + 1) * DIN + i] = acc1;
}

// score[b][h][s] = x2[b][s][:].w[b][h][:] + cK.  grid (4096/64, 16), block 256.
// Wave handles 4 heads for 64 s-rows; w loads are wave-uniform -> s_load.
__global__ __launch_bounds__(256) void k_scores(const float* __restrict__ x2,
                                                const float* __restrict__ w,
                                                const float* __restrict__ cK,
                                                float* __restrict__ sc) {
    const int b = blockIdx.y;
    const int l = threadIdx.x & 63;
    const int s = blockIdx.x * 64 + l;
    const int h0 = wave_id() * 4;
    const float* xr = x2 + ((size_t)b * SS + s) * DIN;
    const float* w0 = w + (size_t)(b * NH + h0) * DIN;  // uniform
    float a0 = 0.f, a1 = 0.f, a2 = 0.f, a3 = 0.f;
#pragma unroll 4
    for (int i = 0; i < DIN; i += 4) {
        float4 x4 = *(const float4*)(xr + i);
        float4 q0 = *(const float4*)(w0 + i);
        float4 q1 = *(const float4*)(w0 + DIN + i);
        float4 q2 = *(const float4*)(w0 + 2 * DIN + i);
        float4 q3 = *(const float4*)(w0 + 3 * DIN + i);
        a0 += x4.x * q0.x + x4.y * q0.y + x4.z * q0.z + x4.w * q0.w;
        a1 += x4.x * q1.x + x4.y * q1.y + x4.z * q1.z + x4.w * q1.w;
        a2 += x4.x * q2.x + x4.y * q2.y + x4.z * q2.z + x4.w * q2.w;
        a3 += x4.x * q3.x + x4.y * q3.y + x4.z * q3.z + x4.w * q3.w;
    }
    const size_t base = (size_t)(b * NH + h0) * SS + s;
    sc[base + 0 * SS] = a0 + cK[b * NH + h0 + 0];
    sc[base + 1 * SS] = a1 + cK[b * NH + h0 + 1];
    sc[base + 2 * SS] = a2 + cK[b * NH + h0 + 2];
    sc[base + 3 * SS] = a3 + cK[b * NH + h0 + 3];
}

// In-place softmax over each row of 4096 (with 1/8 logit scale). grid 256.
__global__ __launch_bounds__(256) void k_softmax(float* __restrict__ sc) {
    float* row = sc + (size_t)blockIdx.x * SS;
    float v[16];
    float m = -1e30f;
#pragma unroll
    for (int j = 0; j < 16; ++j) {
        v[j] = row[j * 256 + threadIdx.x];
        m = fmaxf(m, v[j]);
    }
    __shared__ float red[256];
    red[threadIdx.x] = m;
    __syncthreads();
    for (int s = 128; s > 0; s >>= 1) {
        if (threadIdx.x < (unsigned)s)
            red[threadIdx.x] = fmaxf(red[threadIdx.x], red[threadIdx.x + s]);
        __syncthreads();
    }
    m = red[0];
    __syncthreads();
    float sum = 0.f;
#pragma unroll
    for (int j = 0; j < 16; ++j) {
        v[j] = expf((v[j] - m) * 0.125f);
        sum += v[j];
    }
    red[threadIdx.x] = sum;
    __syncthreads();
    for (int s = 128; s > 0; s >>= 1) {
        if (threadIdx.x < (unsigned)s) red[threadIdx.x] += red[threadIdx.x + s];
        __syncthreads();
    }
    const float inv = 1.f / red[0];
#pragma unroll
    for (int j = 0; j < 16; ++j) row[j * 256 + threadIdx.x] = v[j] * inv;
}

// gpart[b][ch][h][i] partial of g = sum_s a[b][h][s]*x3[b][s][i].
// grid (nch, 16), block 256; wave = 4 heads, lane owns 8 i-columns.
__global__ __launch_bounds__(256) void k_gpart(const float* __restrict__ x3,
                                               const float* __restrict__ a,
                                               float* __restrict__ gp,
                                               int schunk) {
    const int b = blockIdx.y, ch = blockIdx.x;
    const int s0 = ch * schunk;
    const int l = threadIdx.x & 63;
    const int h0 = wave_id() * 4;
    const float* ar = a + (size_t)(b * NH + h0) * SS;  // uniform
    float acc[4][8];
#pragma unroll
    for (int hh = 0; hh < 4; ++hh)
#pragma unroll
        for (int j = 0; j < 8; ++j) acc[hh][j] = 0.f;

#pragma unroll 2
    for (int s = s0; s < s0 + schunk; ++s) {
        const float* xr = x3 + ((size_t)b * SS + s) * DIN + l * 8;
        float4 xa = *(const float4*)(xr);
        float4 xb = *(const float4*)(xr + 4);
        float xv[8] = {xa.x, xa.y, xa.z, xa.w, xb.x, xb.y, xb.z, xb.w};
        float w0 = ar[s], w1 = ar[SS + s], w2 = ar[2 * SS + s], w3 = ar[3 * SS + s];
#pragma unroll
        for (int j = 0; j < 8; ++j) {
            acc[0][j] += w0 * xv[j];
            acc[1][j] += w1 * xv[j];
            acc[2][j] += w2 * xv[j];
            acc[3][j] += w3 * xv[j];
        }
    }
#pragma unroll
    for (int hh = 0; hh < 4; ++hh) {
        float* dst = gp + ((size_t)(b * gridDim.x + ch) * NH + (h0 + hh)) * DIN + l * 8;
#pragma unroll
        for (int j = 0; j < 8; ++j) dst[j] = acc[hh][j];
    }
}

// g[pair][i] = sum_ch gpart[b][ch][h][i].  grid 256.
__global__ __launch_bounds__(256) void k_greduce(const float* __restrict__ gp, int nch,
                                                 float* __restrict__ g) {
    const int pair = blockIdx.x;
    const int b = pair >> 4, h = pair & 15;
#pragma unroll
    for (int kk = 0; kk < 2; ++kk) {
        const int i = kk * 256 + threadIdx.x;
        float acc = 0.f;
        for (int ch = 0; ch < nch; ++ch)
            acc += gp[((size_t)(b * nch + ch) * NH + h) * DIN + i];
        g[(size_t)pair * DIN + i] = acc;
    }
}

// G2[p][c] = sum_i g[p][i]*We2[i][c] + be2[c].  grid (1024/64, 256/8), block 256.
__global__ __launch_bounds__(256) void k_g2(const float* __restrict__ g,
                                            const float* __restrict__ We2,
                                            const float* __restrict__ be2,
                                            float* __restrict__ G2) {
    const int c = blockIdx.x * 64 + (threadIdx.x & 63);
    const int p0 = blockIdx.y * 8 + wave_id() * 2;
    const float* g0 = g + (size_t)p0 * DIN;  // uniform
    const float* g1 = g0 + DIN;
    float acc0 = be2[c], acc1 = be2[c];
#pragma unroll 4
    for (int i = 0; i < DIN; ++i) {
        const float wv = We2[(size_t)i * DD + c];
        acc0 += g0[i] * wv;
        acc1 += g1[i] * wv;
    }
    G2[(size_t)p0 * DD + c] = acc0;
    G2[(size_t)(p0 + 1) * DD + c] = acc1;
}

// av[b][h*64+d] = sum_c G2[pair][c]*Wv[c][h*64+d] + bv[h*64+d].  grid 256.
__global__ __launch_bounds__(256) void k_av(const float* __restrict__ G2,
                                            const float* __restrict__ Wv,
                                            const float* __restrict__ bv,
                                            float* __restrict__ av) {
    const int pair = blockIdx.x;
    const int b = pair >> 4, h = pair & 15;
    const int d = threadIdx.x & 63;
    const int part = wave_id();
    const float* gr = G2 + (size_t)pair * DD;  // uniform
    float acc = 0.f;
#pragma unroll 4
    for (int c = part * 256; c < part * 256 + 256; ++c)
        acc += gr[c] * Wv[(size_t)c * DD + h * HD + d];
    __shared__ float red[256];
    red[threadIdx.x] = acc;
    __syncthreads();
    if (threadIdx.x < 64) {
        float r = red[d] + red[64 + d] + red[128 + d] + red[192 + d] + bv[h * HD + d];
        av[(size_t)b * DD + h * HD + d] = r;
    }
}

extern "C" void kernel_launch(void* const* d_in, const int* in_sizes, int n_in,
                              void* d_out, int out_size, void* d_ws, size_t ws_size,
                              hipStream_t stream) {
    const float* x1  = (const float*)d_in[0];
    const float* x2  = (const float*)d_in[1];
    const float* x3  = (const float*)d_in[2];
    const float* We1 = (const float*)d_in[3];
    const float* be1 = (const float*)d_in[4];
    const float* We2 = (const float*)d_in[5];
    const float* be2 = (const float*)d_in[6];
    const float* Wq  = (const float*)d_in[7];
    const float* bq  = (const float*)d_in[8];
    const float* Wk  = (const float*)d_in[9];
    const float* bk  = (const float*)d_in[10];
    const float* Wv  = (const float*)d_in[11];
    const float* bv  = (const float*)d_in[12];
    const float* Wo  = (const float*)d_in[13];
    const float* bo  = (const float*)d_in[14];
    float* out = (float*)d_out;

    char* ws = (char*)d_ws;
    size_t off = 0;
    auto alloc = [&](size_t bytes) -> void* {
        void* p = ws + off;
        off = (off + bytes + 255) & ~(size_t)255;
        return p;
    };
    float* x1e = (float*)alloc((size_t)BB * DD * 4);
    float* qb  = (float*)alloc((size_t)BB * DD * 4);
    float* u   = (float*)alloc((size_t)BB * NH * DD * 4);
    float* cK  = (float*)alloc((size_t)BB * NH * 4);
    float* wv_ = (float*)alloc((size_t)BB * NH * DIN * 4);
    float* sc  = (float*)alloc((size_t)BB * NH * SS * 4);
    float* g   = (float*)alloc((size_t)BB * NH * DIN * 4);
    float* G2  = (float*)alloc((size_t)BB * NH * DD * 4);
    float* av  = (float*)alloc((size_t)BB * DD * 4);

    // gpart sized to fit remaining workspace: nch chunks of [16b][16h][512i].
    const size_t per_chunk = (size_t)BB * NH * DIN * 4;  // 512 KB
    int nch = 32;
    while (nch > 8 && off + (size_t)nch * per_chunk > ws_size) nch >>= 1;
    float* gp = (float*)alloc((size_t)nch * per_chunk);
    const int schunk = SS / nch;

    k_rowvec_mm<DIN><<<dim3(DD / 256, BB), 256, 0, stream>>>(x1, We1, be1, x1e);
    k_rowvec_mm<DD><<<dim3(DD / 256, BB), 256, 0, stream>>>(x1e, Wq, bq, qb);
    k_u<<<dim3(NH, BB), 256, 0, stream>>>(qb, Wk, bk, be2, u, cK);
    k_w<<<dim3(DIN / 64, BB * NH / 8), 256, 0, stream>>>(u, We2, wv_);
    k_scores<<<dim3(SS / 64, BB), 256, 0, stream>>>(x2, wv_, cK, sc);
    k_softmax<<<BB * NH, 256, 0, stream>>>(sc);
    k_gpart<<<dim3(nch, BB), 256, 0, stream>>>(x3, sc, gp, schunk);
    k_greduce<<<BB * NH, 256, 0, stream>>>(gp, nch, g);
    k_g2<<<dim3(DD / 64, BB * NH / 8), 256, 0, stream>>>(g, We2, be2, G2);
    k_av<<<BB * NH, 256, 0, stream>>>(G2, Wv, bv, av);
    k_rowvec_mm<DD><<<dim3(DD / 256, BB), 256, 0, stream>>>(av, Wo, bo, out);
}